// Round 11
// baseline (83.277 us; speedup 1.0000x reference)
//
#include <hip/hip_runtime.h>
#include <math.h>

#define BB 4
#define TT 2048
#define DIMM 512
#define HEADS 8
#define HDIM 64
#define RANKK 256
#define WINN 256

static constexpr int BT = BB * TT; // 8192
#define SC2 0.1803368801111244f   // 0.125 * log2(e)

typedef short bf8_t __attribute__((ext_vector_type(8)));   // 8 bf16 payload
typedef float f32x4 __attribute__((ext_vector_type(4)));

__device__ __forceinline__ unsigned f2bf2(float a, float b) {  // lo=a, hi=b, RNE
    unsigned r;
    asm("v_cvt_pk_bf16_f32 %0, %1, %2" : "=v"(r) : "v"(a), "v"(b));
    return r;
}

typedef __attribute__((address_space(1))) void gvoid_t;
typedef __attribute__((address_space(3))) void lvoid_t;
__device__ __forceinline__ void gload16(const void* g, void* l) {
    __builtin_amdgcn_global_load_lds((gvoid_t*)g, (lvoid_t*)l, 16, 0, 0);
}
#define WAIT_VM0_BARRIER() do { \
    asm volatile("s_waitcnt vmcnt(0)" ::: "memory"); \
    __builtin_amdgcn_s_barrier(); \
    __builtin_amdgcn_sched_barrier(0); \
} while (0)

// ---------------- fused prep: trig table + all f32->bf16 conversions ----------
__device__ __forceinline__ void cvt4(const float* __restrict__ s,
                                     unsigned short* __restrict__ d, int i) {
    float4 v = *reinterpret_cast<const float4*>(s + i);
    uint2 st = make_uint2(f2bf2(v.x, v.y), f2bf2(v.z, v.w));
    *reinterpret_cast<uint2*>(d + i) = st;
}

__global__ __launch_bounds__(256) void prep_kernel(
    const float* __restrict__ x, const float* __restrict__ Wq,
    const float* __restrict__ Wkd, const float* __restrict__ Wku,
    const float* __restrict__ wn, const float* __restrict__ Wout,
    unsigned short* __restrict__ xb, unsigned short* __restrict__ wcomb,
    unsigned short* __restrict__ wkub, unsigned short* __restrict__ woutb,
    float* __restrict__ cosT, float* __restrict__ sinT) {
    int bid = blockIdx.x;
    if (bid < 4096) {
        cvt4(x, xb, (bid * 256 + threadIdx.x) * 4);
    } else if (bid < 4352) {
        cvt4(Wq, wcomb, ((bid - 4096) * 256 + threadIdx.x) * 4);
    } else if (bid < 4480) {
        cvt4(Wkd, wcomb + DIMM * DIMM, ((bid - 4352) * 256 + threadIdx.x) * 4);
    } else if (bid < 4736) {
        int i = ((bid - 4480) * 256 + threadIdx.x) * 4;
        float4 v = *reinterpret_cast<const float4*>(Wku + i);
        float4 s = *reinterpret_cast<const float4*>(wn + (i & 255));
        uint2 st = make_uint2(f2bf2(v.x * s.x, v.y * s.y), f2bf2(v.z * s.z, v.w * s.w));
        *reinterpret_cast<uint2*>(wkub + i) = st;
    } else if (bid < 4992) {
        cvt4(Wout, woutb, ((bid - 4736) * 256 + threadIdx.x) * 4);
    } else {
        int idx = (bid - 4992) * 256 + threadIdx.x; // < 65536
        int t = idx >> 5, f = idx & 31;
        // freq_rev = 10000^(-f/32) / (2*pi) in f64 (one exp2); angle in revolutions
        double frev = exp2(-(double)f * 0.4152410118609203) * 0.15915494309189535;
        double a = (double)t * frev;
        float fr = (float)(a - floor(a));       // [0,1) revolution, exact reduction
        cosT[idx] = cospif(2.0f * fr);
        sinT[idx] = sinpif(2.0f * fr);
    }
}

// ---------------- bf16 MFMA GEMM, BK=64, swizzled LDS, fused epilogues --------
// BMx128 tile, BM/16 waves of 32x64, 2-phase dbuf, global_load_lds staging
// with pre-swizzled source (dest chunk c holds global chunk c^(row&7)).
// MODE 0: plain f32 C (out = aob @ Wout^T)                         [BM=64]
// MODE 1: cols<512 -> q-RoPE -> O1 (qb); cols>=512 -> bf16 -> O2 (ckvb0)
//         + per-row sumsq partials -> ssum[4][8192]                [BM=128]
// MODE 2: cols<512 -> k-RoPE*rinv -> O1 (kb); cols>=512 -> V^T*rinv -> O2 (vT);
//         rinv computed from ssum                                  [BM=128]
template<int MODE, int BM>
__global__ __launch_bounds__(BM * 4) void gemm_bf(const unsigned short* __restrict__ A,
                                                  const unsigned short* __restrict__ W,
                                                  float* __restrict__ Cf,
                                                  unsigned short* __restrict__ O1,
                                                  unsigned short* __restrict__ O2,
                                                  const float* __restrict__ cosT,
                                                  const float* __restrict__ sinT,
                                                  float* __restrict__ ssum,
                                                  int K, int N) {
    __shared__ __align__(16) unsigned short As[2][BM * 64];
    __shared__ __align__(16) unsigned short Ws[2][128 * 64];
    const int tid = threadIdx.x;
    const int lane = tid & 63, w = tid >> 6;       // BM/16 waves
    const int lr = lane & 15, hi = lane >> 4;
    const int m0 = blockIdx.x * BM, n0 = blockIdx.y * 128;
    const int wr = (w >> 1) * 32, wc = (w & 1) * 64;   // wave tile 32 rows x 64 cols

    f32x4 acc[2][4];
#pragma unroll
    for (int i = 0; i < 2; ++i)
#pragma unroll
        for (int j = 0; j < 4; ++j) acc[i][j] = 0.0f;

    const int NT = K >> 6;
    auto stage = [&](int t, int b) {
        const int kt = t * 64;
#pragma unroll
        for (int c = tid; c < BM * 8; c += BM * 4) {
            int row = c >> 3, sc = ((c & 7) ^ (row & 7)) << 3;
            gload16(A + (size_t)(m0 + row) * K + kt + sc, &As[b][c * 8]);
        }
#pragma unroll
        for (int c = tid; c < 1024; c += BM * 4) {
            int row = c >> 3, sc = ((c & 7) ^ (row & 7)) << 3;
            gload16(W + (size_t)(n0 + row) * K + kt + sc, &Ws[b][c * 8]);
        }
    };

    stage(0, 0);
    WAIT_VM0_BARRIER();
    for (int t = 0; t < NT; ++t) {
        const int cur = t & 1;
        if (t + 1 < NT) stage(t + 1, cur ^ 1);
        bf8_t af[2][2], bw[4][2];
#pragma unroll
        for (int i = 0; i < 2; ++i) {
            int row = wr + i * 16 + lr;
#pragma unroll
            for (int kk = 0; kk < 2; ++kk)
                af[i][kk] = *reinterpret_cast<const bf8_t*>(
                    &As[cur][row * 64 + (((kk * 4 + hi) ^ (row & 7)) << 3)]);
        }
#pragma unroll
        for (int j = 0; j < 4; ++j) {
            int row = wc + j * 16 + lr;
#pragma unroll
            for (int kk = 0; kk < 2; ++kk)
                bw[j][kk] = *reinterpret_cast<const bf8_t*>(
                    &Ws[cur][row * 64 + (((kk * 4 + hi) ^ (row & 7)) << 3)]);
        }
#pragma unroll
        for (int kk = 0; kk < 2; ++kk)
#pragma unroll
            for (int i = 0; i < 2; ++i)
#pragma unroll
                for (int j = 0; j < 4; ++j)
                    acc[i][j] = __builtin_amdgcn_mfma_f32_16x16x32_bf16(af[i][kk], bw[j][kk], acc[i][j], 0, 0, 0);
        if (t + 1 < NT) WAIT_VM0_BARRIER();
    }

    if constexpr (MODE == 0) {
#pragma unroll
        for (int i = 0; i < 2; ++i)
#pragma unroll
            for (int j = 0; j < 4; ++j)
#pragma unroll
                for (int r = 0; r < 4; ++r)
                    Cf[(size_t)(m0 + wr + i * 16 + 4 * hi + r) * N + n0 + wc + j * 16 + lr] = acc[i][j][r];
    } else if (n0 < 512) {
        // RoPE epilogue -> O1 in [B*H, T, HD] bf16 (MODE 2 additionally scales by rinv)
        int h = (n0 + wc) >> 6;
#pragma unroll
        for (int i = 0; i < 2; ++i) {
            int tb = m0 + wr + i * 16 + 4 * hi;
            float4 rv4 = make_float4(1.f, 1.f, 1.f, 1.f);
            if constexpr (MODE == 2) {
                float4 sa = *reinterpret_cast<const float4*>(ssum + tb);
                float4 sb = *reinterpret_cast<const float4*>(ssum + 8192 + tb);
                float4 sc = *reinterpret_cast<const float4*>(ssum + 16384 + tb);
                float4 sd = *reinterpret_cast<const float4*>(ssum + 24576 + tb);
                rv4.x = rsqrtf((sa.x + sb.x + sc.x + sd.x) * (1.0f / RANKK) + 1e-6f);
                rv4.y = rsqrtf((sa.y + sb.y + sc.y + sd.y) * (1.0f / RANKK) + 1e-6f);
                rv4.z = rsqrtf((sa.z + sb.z + sc.z + sd.z) * (1.0f / RANKK) + 1e-6f);
                rv4.w = rsqrtf((sa.w + sb.w + sc.w + sd.w) * (1.0f / RANKK) + 1e-6f);
            }
#pragma unroll
            for (int j = 0; j < 2; ++j)
#pragma unroll
                for (int r = 0; r < 4; ++r) {
                    int t = tb + r;
                    int b = t >> 11, tt = t & 2047;
                    int ff = j * 16 + lr;
                    float rv = (&rv4.x)[r];
                    float x1 = acc[i][j][r] * rv, x2 = acc[i][j + 2][r] * rv;
                    float cc = cosT[tt * 32 + ff], ss = sinT[tt * 32 + ff];
                    unsigned u = f2bf2(x1 * cc - x2 * ss, x2 * cc + x1 * ss);
                    unsigned short* dp = O1 + ((size_t)((b * 8 + h) * 2048 + tt)) * 64;
                    dp[ff]      = (unsigned short)u;
                    dp[ff + 32] = (unsigned short)(u >> 16);
                }
        }
    } else if constexpr (MODE == 1) {
        // ckv region: bf16 compact [B*T, 256] + deterministic per-row sumsq partials
        int cb = n0 - 512 + wc;
        int part = ((n0 - 512) >> 7) * 2 + (w & 1);
#pragma unroll
        for (int i = 0; i < 2; ++i) {
            int tb = m0 + wr + i * 16 + 4 * hi;
#pragma unroll
            for (int r = 0; r < 4; ++r) {
                float ps = acc[i][0][r] * acc[i][0][r] + acc[i][1][r] * acc[i][1][r]
                         + acc[i][2][r] * acc[i][2][r] + acc[i][3][r] * acc[i][3][r];
                ps += __shfl_xor(ps, 1);
                ps += __shfl_xor(ps, 2);
                ps += __shfl_xor(ps, 4);
                ps += __shfl_xor(ps, 8);
                if (lr == 0) ssum[part * 8192 + tb + r] = ps;
            }
#pragma unroll
            for (int j = 0; j < 4; ++j) {
                unsigned a01 = f2bf2(acc[i][j][0], acc[i][j][1]);
                unsigned a23 = f2bf2(acc[i][j][2], acc[i][j][3]);
                unsigned short* dp = O2 + (size_t)tb * 256 + cb + j * 16 + lr;
                dp[0]   = (unsigned short)a01;
                dp[256] = (unsigned short)(a01 >> 16);
                dp[512] = (unsigned short)a23;
                dp[768] = (unsigned short)(a23 >> 16);
            }
        }
    } else {
        // MODE 2, V region: transposed pack * rinv -> vT [B*H, HD, T] bf16
        int cb = n0 + wc - 512;
        int h = cb >> 6;
#pragma unroll
        for (int i = 0; i < 2; ++i) {
            int tb = m0 + wr + i * 16 + 4 * hi;
            int b = tb >> 11, tt = tb & 2047;
            float4 sa = *reinterpret_cast<const float4*>(ssum + tb);
            float4 sb = *reinterpret_cast<const float4*>(ssum + 8192 + tb);
            float4 sc = *reinterpret_cast<const float4*>(ssum + 16384 + tb);
            float4 sd = *reinterpret_cast<const float4*>(ssum + 24576 + tb);
            float4 rv4;
            rv4.x = rsqrtf((sa.x + sb.x + sc.x + sd.x) * (1.0f / RANKK) + 1e-6f);
            rv4.y = rsqrtf((sa.y + sb.y + sc.y + sd.y) * (1.0f / RANKK) + 1e-6f);
            rv4.z = rsqrtf((sa.z + sb.z + sc.z + sd.z) * (1.0f / RANKK) + 1e-6f);
            rv4.w = rsqrtf((sa.w + sb.w + sc.w + sd.w) * (1.0f / RANKK) + 1e-6f);
#pragma unroll
            for (int j = 0; j < 4; ++j) {
                int hd = j * 16 + lr;
                uint2 st = make_uint2(f2bf2(acc[i][j][0] * rv4.x, acc[i][j][1] * rv4.y),
                                      f2bf2(acc[i][j][2] * rv4.z, acc[i][j][3] * rv4.w));
                *reinterpret_cast<uint2*>(O2 + (((size_t)(b * 8 + h) * 64 + hd) * 2048 + tt)) = st;
            }
        }
    }
}

// ---------------- MFMA flash attention, QBLK=256, 32 queries/wave, 8 waves ----
// 256 blocks (XCD-swizzled), 512 thr. 64-key tiles, fixed-max softmax.
// K/V fragments reused across 2 query-frags (halves per-query LDS reads);
// fully-masked tiles skipped per-wave (wave-uniform; barriers stay global).
__global__ __launch_bounds__(512) void attn_mfma(const unsigned short* __restrict__ qbf,
                                                 const unsigned short* __restrict__ kbf,
                                                 const unsigned short* __restrict__ vT,
                                                 unsigned short* __restrict__ aob) {
    __shared__ __align__(16) unsigned short Kl[2][64 * 64];
    __shared__ __align__(16) unsigned short Vl[2][64 * 64];
    __shared__ unsigned short Pl[256][72];
    const int tid = threadIdx.x;
    const int lane = tid & 63, w = tid >> 6;        // 8 waves, 32 queries each
    const int lr = lane & 15, hi = lane >> 4;

    // bijective XCD swizzle: 256 = 8 XCDs x 32; each XCD owns 4 bh values
    const int fid = blockIdx.x;
    const int swz = (fid & 7) * 32 + (fid >> 3);
    const int t0 = (swz & 7) * 256;
    const int bh = swz >> 3;
    const int wq0 = w * 32;                         // wave's first query offset

    bf8_t qa[2][2];
#pragma unroll
    for (int qr = 0; qr < 2; ++qr) {
        const unsigned short* qp = qbf + ((size_t)bh * TT + t0 + wq0 + qr * 16 + lr) * HDIM;
        qa[qr][0] = *reinterpret_cast<const bf8_t*>(qp + hi * 8);
        qa[qr][1] = *reinterpret_cast<const bf8_t*>(qp + 32 + hi * 8);
    }

    f32x4 oc[2][4];
#pragma unroll
    for (int qr = 0; qr < 2; ++qr)
#pragma unroll
        for (int f = 0; f < 4; ++f) oc[qr][f] = 0.0f;
    float lp[2][4] = {{0.f, 0.f, 0.f, 0.f}, {0.f, 0.f, 0.f, 0.f}};

    const int smin = max(0, t0 - WINN);
    const int smax = min(TT, t0 + 256 + WINN);
    const int NT = (smax - smin) >> 6;

    const int st_row = tid >> 3;            // 0..63
    const int st_cs = ((tid & 7) ^ (st_row & 7)) << 3;   // pre-swizzled source offset

    auto stage = [&](int t, int b) {
        const int s0 = smin + t * 64;
        gload16(kbf + ((size_t)bh * TT + s0 + st_row) * HDIM + st_cs, &Kl[b][tid * 8]);
        gload16(vT + ((size_t)bh * 64 + st_row) * TT + s0 + st_cs, &Vl[b][tid * 8]);
    };

    stage(0, 0);
    WAIT_VM0_BARRIER();
    for (int t = 0; t < NT; ++t) {
        const int cur = t & 1;
        if (t + 1 < NT) stage(t + 1, cur ^ 1);
        const int s0 = smin + t * 64;
        const int off_w = s0 - t0 - wq0;    // tile start rel. wave's first query
        // any (key k in [0,63], query q in [0,31]) with |off_w + k - q| <= WINN?
        const bool active = (off_w >= -(WINN + 63)) && (off_w <= WINN + 31);

        if (active) {
            // QK^T: S[32q][64key] per wave; kb reused across both query-frags
            f32x4 sacc[2][4];
#pragma unroll
            for (int qr = 0; qr < 2; ++qr)
#pragma unroll
                for (int f = 0; f < 4; ++f) sacc[qr][f] = 0.0f;
            __builtin_amdgcn_s_setprio(1);
#pragma unroll
            for (int ks = 0; ks < 2; ++ks)
#pragma unroll
                for (int f = 0; f < 4; ++f) {
                    int row = f * 16 + lr;
                    bf8_t kb = *reinterpret_cast<const bf8_t*>(
                        &Kl[cur][row * 64 + (((ks * 4 + hi) ^ (row & 7)) << 3)]);
#pragma unroll
                    for (int qr = 0; qr < 2; ++qr)
                        sacc[qr][f] = __builtin_amdgcn_mfma_f32_16x16x32_bf16(qa[qr][ks], kb, sacc[qr][f], 0, 0, 0);
                }
            __builtin_amdgcn_s_setprio(0);

            const bool edge = (off_w + 63 > WINN) || (off_w - 31 < -WINN);
#pragma unroll
            for (int qr = 0; qr < 2; ++qr)
#pragma unroll
                for (int f = 0; f < 4; ++f) {
                    float p[4];
#pragma unroll
                    for (int r = 0; r < 4; ++r) {
                        float v;
                        if (edge) {
                            int d = off_w + f * 16 + lr - qr * 16 - 4 * hi - r;
                            v = (d <= WINN && d >= -WINN) ? exp2f(sacc[qr][f][r] * SC2) : 0.f;
                        } else {
                            v = exp2f(sacc[qr][f][r] * SC2);
                        }
                        p[r] = v;
                        lp[qr][r] += v;
                    }
                    unsigned a01 = f2bf2(p[0], p[1]);
                    unsigned a23 = f2bf2(p[2], p[3]);
                    unsigned short* bp = &Pl[wq0 + qr * 16 + 4 * hi][f * 16 + lr];
                    bp[0]   = (unsigned short)a01;
                    bp[72]  = (unsigned short)(a01 >> 16);
                    bp[144] = (unsigned short)a23;
                    bp[216] = (unsigned short)(a23 >> 16);
                }

            // PV: out[32q][64hd] += P[32q][64key] * V^T; vb reused across query-frags
            __builtin_amdgcn_s_setprio(1);
#pragma unroll
            for (int ks = 0; ks < 2; ++ks) {
                bf8_t pa[2];
#pragma unroll
                for (int qr = 0; qr < 2; ++qr)
                    pa[qr] = *reinterpret_cast<const bf8_t*>(&Pl[wq0 + qr * 16 + lr][ks * 32 + hi * 8]);
#pragma unroll
                for (int f = 0; f < 4; ++f) {
                    int row = f * 16 + lr;
                    bf8_t vb = *reinterpret_cast<const bf8_t*>(
                        &Vl[cur][row * 64 + (((ks * 4 + hi) ^ (row & 7)) << 3)]);
#pragma unroll
                    for (int qr = 0; qr < 2; ++qr)
                        oc[qr][f] = __builtin_amdgcn_mfma_f32_16x16x32_bf16(pa[qr], vb, oc[qr][f], 0, 0, 0);
                }
            }
            __builtin_amdgcn_s_setprio(0);
        }
        if (t + 1 < NT) WAIT_VM0_BARRIER();
    }

    // deferred l reduction over the 16 lr lanes
#pragma unroll
    for (int qr = 0; qr < 2; ++qr)
#pragma unroll
        for (int r = 0; r < 4; ++r) {
            lp[qr][r] += __shfl_xor(lp[qr][r], 1);
            lp[qr][r] += __shfl_xor(lp[qr][r], 2);
            lp[qr][r] += __shfl_xor(lp[qr][r], 4);
            lp[qr][r] += __shfl_xor(lp[qr][r], 8);
        }

    int b = bh >> 3, h = bh & 7;
#pragma unroll
    for (int qr = 0; qr < 2; ++qr)
#pragma unroll
        for (int r = 0; r < 4; ++r) {
            float inv = 1.0f / lp[qr][r];
            int t = t0 + wq0 + qr * 16 + 4 * hi + r;
            unsigned short* op = aob + ((size_t)b * TT + t) * DIMM + h * HDIM;
            unsigned u0 = f2bf2(oc[qr][0][r] * inv, oc[qr][1][r] * inv);
            unsigned u1 = f2bf2(oc[qr][2][r] * inv, oc[qr][3][r] * inv);
            op[lr]      = (unsigned short)u0;
            op[16 + lr] = (unsigned short)(u0 >> 16);
            op[32 + lr] = (unsigned short)u1;
            op[48 + lr] = (unsigned short)(u1 >> 16);
        }
}

// ---------------- launch ------------------------------------------------------
extern "C" void kernel_launch(void* const* d_in, const int* in_sizes, int n_in,
                              void* d_out, int out_size, void* d_ws, size_t ws_size,
                              hipStream_t stream) {
    const float* x     = (const float*)d_in[0];
    const float* Wq    = (const float*)d_in[1];
    const float* Wkd   = (const float*)d_in[2];
    const float* wnorm = (const float*)d_in[3];
    const float* Wku   = (const float*)d_in[4];
    const float* Wout  = (const float*)d_in[5];
    float* out = (float*)d_out;
    char* ws = (char*)d_ws;

    unsigned short* xb    = (unsigned short*)(ws + 0);          //  8,388,608
    unsigned short* qb    = (unsigned short*)(ws + 8388608);    //  8,388,608
    unsigned short* kb    = (unsigned short*)(ws + 16777216);   //  8,388,608
    unsigned short* vTb   = (unsigned short*)(ws + 25165824);   //  8,388,608
    unsigned short* ckvb0 = (unsigned short*)(ws + 33554432);   //  4,194,304
    unsigned short* aob   = (unsigned short*)(ws + 37748736);   //  8,388,608
    unsigned short* wcomb = (unsigned short*)(ws + 46137344);   //    786,432
    unsigned short* wkub  = (unsigned short*)(ws + 46923776);   //    524,288
    unsigned short* woutb = (unsigned short*)(ws + 47448064);   //    524,288
    float*          cosT  = (float*)(ws + 48005120);            //    262,144
    float*          sinT  = (float*)(ws + 48267264);            //    262,144
    float*          ssum  = (float*)(ws + 48529408);            //    131,072 [4][8192]

    prep_kernel<<<5248, 256, 0, stream>>>(x, Wq, Wkd, Wku, wnorm, Wout,
                                          xb, wcomb, wkub, woutb, cosT, sinT);

    // fused q + kv_down projection (+ q-RoPE, ckv write, sumsq partials): [8192, 768]
    gemm_bf<1, 128><<<dim3(BT / 128, 6), 512, 0, stream>>>(xb, wcomb, nullptr, qb, ckvb0,
                                                           cosT, sinT, ssum, DIMM, 768);

    // kv up-projection (+ k-RoPE*rinv, V^T pack*rinv; rinv from ssum): [8192, 1024]
    gemm_bf<2, 128><<<dim3(BT / 128, 8), 512, 0, stream>>>(ckvb0, wkub, nullptr, kb, vTb,
                                                           cosT, sinT, ssum, RANKK, 1024);

    // attention: 256 blocks, 512 thr (8 waves x 32 queries)
    attn_mfma<<<256, 512, 0, stream>>>(qb, kb, vTb, aob);

    // out = aob @ Wout^T (f32), BM=64 (512 blocks)
    gemm_bf<0, 64><<<dim3(BT / 64, 4), 256, 0, stream>>>(aob, woutb, out, nullptr, nullptr,
                                                         nullptr, nullptr, nullptr, DIMM, DIMM);
}

// Round 12
// 71.930 us; speedup vs baseline: 1.1577x; 1.1577x over previous
//
#include <hip/hip_runtime.h>
#include <math.h>

#define BB 4
#define TT 2048
#define DIMM 512
#define HEADS 8
#define HDIM 64
#define RANKK 256
#define WINN 256

static constexpr int BT = BB * TT; // 8192
#define SC2 0.1803368801111244f   // 0.125 * log2(e)

typedef short bf8_t __attribute__((ext_vector_type(8)));   // 8 bf16 payload
typedef float f32x4 __attribute__((ext_vector_type(4)));

__device__ __forceinline__ unsigned f2bf2(float a, float b) {  // lo=a, hi=b, RNE
    unsigned r;
    asm("v_cvt_pk_bf16_f32 %0, %1, %2" : "=v"(r) : "v"(a), "v"(b));
    return r;
}

typedef __attribute__((address_space(1))) void gvoid_t;
typedef __attribute__((address_space(3))) void lvoid_t;
__device__ __forceinline__ void gload16(const void* g, void* l) {
    __builtin_amdgcn_global_load_lds((gvoid_t*)g, (lvoid_t*)l, 16, 0, 0);
}
#define WAIT_VM0_BARRIER() do { \
    asm volatile("s_waitcnt vmcnt(0)" ::: "memory"); \
    __builtin_amdgcn_s_barrier(); \
    __builtin_amdgcn_sched_barrier(0); \
} while (0)

// ---------------- fused prep: trig table + all f32->bf16 conversions ----------
__device__ __forceinline__ void cvt4(const float* __restrict__ s,
                                     unsigned short* __restrict__ d, int i) {
    float4 v = *reinterpret_cast<const float4*>(s + i);
    uint2 st = make_uint2(f2bf2(v.x, v.y), f2bf2(v.z, v.w));
    *reinterpret_cast<uint2*>(d + i) = st;
}

__global__ __launch_bounds__(256) void prep_kernel(
    const float* __restrict__ x, const float* __restrict__ Wq,
    const float* __restrict__ Wkd, const float* __restrict__ Wku,
    const float* __restrict__ wn, const float* __restrict__ Wout,
    unsigned short* __restrict__ xb, unsigned short* __restrict__ wcomb,
    unsigned short* __restrict__ wkub, unsigned short* __restrict__ woutb,
    float* __restrict__ cosT, float* __restrict__ sinT) {
    int bid = blockIdx.x;
    if (bid < 4096) {
        cvt4(x, xb, (bid * 256 + threadIdx.x) * 4);
    } else if (bid < 4352) {
        cvt4(Wq, wcomb, ((bid - 4096) * 256 + threadIdx.x) * 4);
    } else if (bid < 4480) {
        cvt4(Wkd, wcomb + DIMM * DIMM, ((bid - 4352) * 256 + threadIdx.x) * 4);
    } else if (bid < 4736) {
        int i = ((bid - 4480) * 256 + threadIdx.x) * 4;
        float4 v = *reinterpret_cast<const float4*>(Wku + i);
        float4 s = *reinterpret_cast<const float4*>(wn + (i & 255));
        uint2 st = make_uint2(f2bf2(v.x * s.x, v.y * s.y), f2bf2(v.z * s.z, v.w * s.w));
        *reinterpret_cast<uint2*>(wkub + i) = st;
    } else if (bid < 4992) {
        cvt4(Wout, woutb, ((bid - 4736) * 256 + threadIdx.x) * 4);
    } else {
        int idx = (bid - 4992) * 256 + threadIdx.x; // < 65536
        int t = idx >> 5, f = idx & 31;
        // freq_rev = 10000^(-f/32) / (2*pi) in f64 (one exp2); angle in revolutions
        double frev = exp2(-(double)f * 0.4152410118609203) * 0.15915494309189535;
        double a = (double)t * frev;
        float fr = (float)(a - floor(a));       // [0,1) revolution, exact reduction
        cosT[idx] = cospif(2.0f * fr);
        sinT[idx] = sinpif(2.0f * fr);
    }
}

// ---------------- bf16 MFMA GEMM, BK=64, swizzled LDS, fused epilogues --------
// BMx128 tile, BM/16 waves of 32x64, 2-phase dbuf, global_load_lds staging
// with pre-swizzled source (dest chunk c holds global chunk c^(row&7)).
// MODE 0: plain f32 C (out = aob @ Wout^T)                         [BM=64]
// MODE 1: cols<512 -> q-RoPE -> O1 (qb); cols>=512 -> bf16 -> O2 (ckvb0)
//         + per-row sumsq partials -> ssum[4][8192]                [BM=128]
// MODE 2: cols<512 -> k-RoPE*rinv -> O1 (kb); cols>=512 -> V^T*rinv -> O2 (vT);
//         rinv computed from ssum                                  [BM=128]
template<int MODE, int BM>
__global__ __launch_bounds__(BM * 4) void gemm_bf(const unsigned short* __restrict__ A,
                                                  const unsigned short* __restrict__ W,
                                                  float* __restrict__ Cf,
                                                  unsigned short* __restrict__ O1,
                                                  unsigned short* __restrict__ O2,
                                                  const float* __restrict__ cosT,
                                                  const float* __restrict__ sinT,
                                                  float* __restrict__ ssum,
                                                  int K, int N) {
    __shared__ __align__(16) unsigned short As[2][BM * 64];
    __shared__ __align__(16) unsigned short Ws[2][128 * 64];
    const int tid = threadIdx.x;
    const int lane = tid & 63, w = tid >> 6;       // BM/16 waves
    const int lr = lane & 15, hi = lane >> 4;
    const int m0 = blockIdx.x * BM, n0 = blockIdx.y * 128;
    const int wr = (w >> 1) * 32, wc = (w & 1) * 64;   // wave tile 32 rows x 64 cols

    f32x4 acc[2][4];
#pragma unroll
    for (int i = 0; i < 2; ++i)
#pragma unroll
        for (int j = 0; j < 4; ++j) acc[i][j] = 0.0f;

    const int NT = K >> 6;
    auto stage = [&](int t, int b) {
        const int kt = t * 64;
#pragma unroll
        for (int c = tid; c < BM * 8; c += BM * 4) {
            int row = c >> 3, sc = ((c & 7) ^ (row & 7)) << 3;
            gload16(A + (size_t)(m0 + row) * K + kt + sc, &As[b][c * 8]);
        }
#pragma unroll
        for (int c = tid; c < 1024; c += BM * 4) {
            int row = c >> 3, sc = ((c & 7) ^ (row & 7)) << 3;
            gload16(W + (size_t)(n0 + row) * K + kt + sc, &Ws[b][c * 8]);
        }
    };

    stage(0, 0);
    WAIT_VM0_BARRIER();
    for (int t = 0; t < NT; ++t) {
        const int cur = t & 1;
        if (t + 1 < NT) stage(t + 1, cur ^ 1);
        bf8_t af[2][2], bw[4][2];
#pragma unroll
        for (int i = 0; i < 2; ++i) {
            int row = wr + i * 16 + lr;
#pragma unroll
            for (int kk = 0; kk < 2; ++kk)
                af[i][kk] = *reinterpret_cast<const bf8_t*>(
                    &As[cur][row * 64 + (((kk * 4 + hi) ^ (row & 7)) << 3)]);
        }
#pragma unroll
        for (int j = 0; j < 4; ++j) {
            int row = wc + j * 16 + lr;
#pragma unroll
            for (int kk = 0; kk < 2; ++kk)
                bw[j][kk] = *reinterpret_cast<const bf8_t*>(
                    &Ws[cur][row * 64 + (((kk * 4 + hi) ^ (row & 7)) << 3)]);
        }
#pragma unroll
        for (int kk = 0; kk < 2; ++kk)
#pragma unroll
            for (int i = 0; i < 2; ++i)
#pragma unroll
                for (int j = 0; j < 4; ++j)
                    acc[i][j] = __builtin_amdgcn_mfma_f32_16x16x32_bf16(af[i][kk], bw[j][kk], acc[i][j], 0, 0, 0);
        if (t + 1 < NT) WAIT_VM0_BARRIER();
    }

    if constexpr (MODE == 0) {
#pragma unroll
        for (int i = 0; i < 2; ++i)
#pragma unroll
            for (int j = 0; j < 4; ++j)
#pragma unroll
                for (int r = 0; r < 4; ++r)
                    Cf[(size_t)(m0 + wr + i * 16 + 4 * hi + r) * N + n0 + wc + j * 16 + lr] = acc[i][j][r];
    } else if (n0 < 512) {
        // RoPE epilogue -> O1 in [B*H, T, HD] bf16 (MODE 2 additionally scales by rinv)
        int h = (n0 + wc) >> 6;
#pragma unroll
        for (int i = 0; i < 2; ++i) {
            int tb = m0 + wr + i * 16 + 4 * hi;
            float4 rv4 = make_float4(1.f, 1.f, 1.f, 1.f);
            if constexpr (MODE == 2) {
                float4 sa = *reinterpret_cast<const float4*>(ssum + tb);
                float4 sb = *reinterpret_cast<const float4*>(ssum + 8192 + tb);
                float4 sc = *reinterpret_cast<const float4*>(ssum + 16384 + tb);
                float4 sd = *reinterpret_cast<const float4*>(ssum + 24576 + tb);
                rv4.x = rsqrtf((sa.x + sb.x + sc.x + sd.x) * (1.0f / RANKK) + 1e-6f);
                rv4.y = rsqrtf((sa.y + sb.y + sc.y + sd.y) * (1.0f / RANKK) + 1e-6f);
                rv4.z = rsqrtf((sa.z + sb.z + sc.z + sd.z) * (1.0f / RANKK) + 1e-6f);
                rv4.w = rsqrtf((sa.w + sb.w + sc.w + sd.w) * (1.0f / RANKK) + 1e-6f);
            }
#pragma unroll
            for (int j = 0; j < 2; ++j)
#pragma unroll
                for (int r = 0; r < 4; ++r) {
                    int t = tb + r;
                    int b = t >> 11, tt = t & 2047;
                    int ff = j * 16 + lr;
                    float rv = (&rv4.x)[r];
                    float x1 = acc[i][j][r] * rv, x2 = acc[i][j + 2][r] * rv;
                    float cc = cosT[tt * 32 + ff], ss = sinT[tt * 32 + ff];
                    unsigned u = f2bf2(x1 * cc - x2 * ss, x2 * cc + x1 * ss);
                    unsigned short* dp = O1 + ((size_t)((b * 8 + h) * 2048 + tt)) * 64;
                    dp[ff]      = (unsigned short)u;
                    dp[ff + 32] = (unsigned short)(u >> 16);
                }
        }
    } else if constexpr (MODE == 1) {
        // ckv region: bf16 compact [B*T, 256] + deterministic per-row sumsq partials
        int cb = n0 - 512 + wc;
        int part = ((n0 - 512) >> 7) * 2 + (w & 1);
#pragma unroll
        for (int i = 0; i < 2; ++i) {
            int tb = m0 + wr + i * 16 + 4 * hi;
#pragma unroll
            for (int r = 0; r < 4; ++r) {
                float ps = acc[i][0][r] * acc[i][0][r] + acc[i][1][r] * acc[i][1][r]
                         + acc[i][2][r] * acc[i][2][r] + acc[i][3][r] * acc[i][3][r];
                ps += __shfl_xor(ps, 1);
                ps += __shfl_xor(ps, 2);
                ps += __shfl_xor(ps, 4);
                ps += __shfl_xor(ps, 8);
                if (lr == 0) ssum[part * 8192 + tb + r] = ps;
            }
#pragma unroll
            for (int j = 0; j < 4; ++j) {
                unsigned a01 = f2bf2(acc[i][j][0], acc[i][j][1]);
                unsigned a23 = f2bf2(acc[i][j][2], acc[i][j][3]);
                unsigned short* dp = O2 + (size_t)tb * 256 + cb + j * 16 + lr;
                dp[0]   = (unsigned short)a01;
                dp[256] = (unsigned short)(a01 >> 16);
                dp[512] = (unsigned short)a23;
                dp[768] = (unsigned short)(a23 >> 16);
            }
        }
    } else {
        // MODE 2, V region: transposed pack * rinv -> vT [B*H, HD, T] bf16
        int cb = n0 + wc - 512;
        int h = cb >> 6;
#pragma unroll
        for (int i = 0; i < 2; ++i) {
            int tb = m0 + wr + i * 16 + 4 * hi;
            int b = tb >> 11, tt = tb & 2047;
            float4 sa = *reinterpret_cast<const float4*>(ssum + tb);
            float4 sb = *reinterpret_cast<const float4*>(ssum + 8192 + tb);
            float4 sc = *reinterpret_cast<const float4*>(ssum + 16384 + tb);
            float4 sd = *reinterpret_cast<const float4*>(ssum + 24576 + tb);
            float4 rv4;
            rv4.x = rsqrtf((sa.x + sb.x + sc.x + sd.x) * (1.0f / RANKK) + 1e-6f);
            rv4.y = rsqrtf((sa.y + sb.y + sc.y + sd.y) * (1.0f / RANKK) + 1e-6f);
            rv4.z = rsqrtf((sa.z + sb.z + sc.z + sd.z) * (1.0f / RANKK) + 1e-6f);
            rv4.w = rsqrtf((sa.w + sb.w + sc.w + sd.w) * (1.0f / RANKK) + 1e-6f);
#pragma unroll
            for (int j = 0; j < 4; ++j) {
                int hd = j * 16 + lr;
                uint2 st = make_uint2(f2bf2(acc[i][j][0] * rv4.x, acc[i][j][1] * rv4.y),
                                      f2bf2(acc[i][j][2] * rv4.z, acc[i][j][3] * rv4.w));
                *reinterpret_cast<uint2*>(O2 + (((size_t)(b * 8 + h) * 64 + hd) * 2048 + tt)) = st;
            }
        }
    }
}

// ---------------- MFMA flash attention, QBLK=128, 2-phase dbuf pipeline -------
// 512 blocks (XCD-swizzled), 512 thr = 8 waves. 64-key tiles, fixed-max softmax.
// Per-wave skip of fully-masked tiles (wave-uniform; staging/barriers global).
__global__ __launch_bounds__(512) void attn_mfma(const unsigned short* __restrict__ qbf,
                                                 const unsigned short* __restrict__ kbf,
                                                 const unsigned short* __restrict__ vT,
                                                 unsigned short* __restrict__ aob) {
    __shared__ __align__(16) unsigned short Kl[2][64 * 64];
    __shared__ __align__(16) unsigned short Vl[2][64 * 64];
    __shared__ unsigned short Pl[128][72];
    const int tid = threadIdx.x;
    const int lane = tid & 63, w = tid >> 6;        // 8 waves
    const int lr = lane & 15, hi = lane >> 4;

    // bijective XCD swizzle: 512 = 8 XCDs x 64; each XCD owns 4 bh values
    const int fid = blockIdx.x;
    const int swz = (fid & 7) * 64 + (fid >> 3);
    const int t0 = (swz & 15) * 128;
    const int bh = swz >> 4;

    const unsigned short* qp = qbf + ((size_t)bh * TT + t0 + w * 16 + lr) * HDIM;
    bf8_t qa[2];
    qa[0] = *reinterpret_cast<const bf8_t*>(qp + hi * 8);
    qa[1] = *reinterpret_cast<const bf8_t*>(qp + 32 + hi * 8);

    f32x4 oc[4];
#pragma unroll
    for (int f = 0; f < 4; ++f) oc[f] = 0.0f;
    float lp[4] = {0.f, 0.f, 0.f, 0.f};

    const int smin = max(0, t0 - WINN);
    const int smax = min(TT, t0 + 128 + WINN);
    const int NT = (smax - smin) >> 6;

    const int st_row = tid >> 3;            // 0..63
    const int st_c = tid & 7;               // 16B chunk
    const int st_cs = (st_c ^ (st_row & 7)) << 3;   // pre-swizzled source elem offset

    auto stage = [&](int t, int b) {
        const int s0 = smin + t * 64;
        gload16(kbf + ((size_t)bh * TT + s0 + st_row) * HDIM + st_cs, &Kl[b][tid * 8]);
        gload16(vT + ((size_t)bh * 64 + st_row) * TT + s0 + st_cs, &Vl[b][tid * 8]);
    };

    stage(0, 0);
    WAIT_VM0_BARRIER();
    for (int t = 0; t < NT; ++t) {
        const int cur = t & 1;
        if (t + 1 < NT) stage(t + 1, cur ^ 1);
        const int s0 = smin + t * 64;
        const int off_w = s0 - t0 - w * 16;
        // wave covers queries [0,15]; tile keys [0,63]: any |off_w + k - q| <= WINN?
        const bool active = (off_w >= -(WINN + 63)) && (off_w <= WINN + 15);

        if (active) {
            // QK^T: S[16q][64key] per wave
            f32x4 sacc[4];
#pragma unroll
            for (int f = 0; f < 4; ++f) sacc[f] = 0.0f;
            __builtin_amdgcn_s_setprio(1);
#pragma unroll
            for (int ks = 0; ks < 2; ++ks)
#pragma unroll
                for (int f = 0; f < 4; ++f) {
                    int row = f * 16 + lr;
                    bf8_t kb = *reinterpret_cast<const bf8_t*>(
                        &Kl[cur][row * 64 + (((ks * 4 + hi) ^ (row & 7)) << 3)]);
                    sacc[f] = __builtin_amdgcn_mfma_f32_16x16x32_bf16(qa[ks], kb, sacc[f], 0, 0, 0);
                }
            __builtin_amdgcn_s_setprio(0);

            const bool edge = (off_w + 63 > WINN) || (off_w - 15 < -WINN);
#pragma unroll
            for (int f = 0; f < 4; ++f) {
                float p[4];
#pragma unroll
                for (int r = 0; r < 4; ++r) {
                    float v;
                    if (edge) {
                        int d = off_w + f * 16 + lr - 4 * hi - r;
                        v = (d <= WINN && d >= -WINN) ? exp2f(sacc[f][r] * SC2) : 0.f;
                    } else {
                        v = exp2f(sacc[f][r] * SC2);
                    }
                    p[r] = v;
                    lp[r] += v;
                }
                unsigned a01 = f2bf2(p[0], p[1]);
                unsigned a23 = f2bf2(p[2], p[3]);
                unsigned short* bp = &Pl[w * 16 + 4 * hi][f * 16 + lr];
                bp[0]   = (unsigned short)a01;
                bp[72]  = (unsigned short)(a01 >> 16);
                bp[144] = (unsigned short)a23;
                bp[216] = (unsigned short)(a23 >> 16);
            }

            // PV: out[16q][64hd] += P[16q][64key] * V^T
            __builtin_amdgcn_s_setprio(1);
#pragma unroll
            for (int ks = 0; ks < 2; ++ks) {
                bf8_t pa = *reinterpret_cast<const bf8_t*>(&Pl[w * 16 + lr][ks * 32 + hi * 8]);
#pragma unroll
                for (int f = 0; f < 4; ++f) {
                    int row = f * 16 + lr;
                    bf8_t vb = *reinterpret_cast<const bf8_t*>(
                        &Vl[cur][row * 64 + (((ks * 4 + hi) ^ (row & 7)) << 3)]);
                    oc[f] = __builtin_amdgcn_mfma_f32_16x16x32_bf16(pa, vb, oc[f], 0, 0, 0);
                }
            }
            __builtin_amdgcn_s_setprio(0);
        }
        if (t + 1 < NT) WAIT_VM0_BARRIER();
    }

    // deferred l reduction over the 16 lr lanes
#pragma unroll
    for (int r = 0; r < 4; ++r) {
        lp[r] += __shfl_xor(lp[r], 1);
        lp[r] += __shfl_xor(lp[r], 2);
        lp[r] += __shfl_xor(lp[r], 4);
        lp[r] += __shfl_xor(lp[r], 8);
    }

    int b = bh >> 3, h = bh & 7;
#pragma unroll
    for (int r = 0; r < 4; ++r) {
        float inv = 1.0f / lp[r];
        int t = t0 + w * 16 + 4 * hi + r;
        unsigned short* op = aob + ((size_t)b * TT + t) * DIMM + h * HDIM;
        unsigned u0 = f2bf2(oc[0][r] * inv, oc[1][r] * inv);
        unsigned u1 = f2bf2(oc[2][r] * inv, oc[3][r] * inv);
        op[lr]      = (unsigned short)u0;
        op[16 + lr] = (unsigned short)(u0 >> 16);
        op[32 + lr] = (unsigned short)u1;
        op[48 + lr] = (unsigned short)(u1 >> 16);
    }
}

// ---------------- launch ------------------------------------------------------
extern "C" void kernel_launch(void* const* d_in, const int* in_sizes, int n_in,
                              void* d_out, int out_size, void* d_ws, size_t ws_size,
                              hipStream_t stream) {
    const float* x     = (const float*)d_in[0];
    const float* Wq    = (const float*)d_in[1];
    const float* Wkd   = (const float*)d_in[2];
    const float* wnorm = (const float*)d_in[3];
    const float* Wku   = (const float*)d_in[4];
    const float* Wout  = (const float*)d_in[5];
    float* out = (float*)d_out;
    char* ws = (char*)d_ws;

    unsigned short* xb    = (unsigned short*)(ws + 0);          //  8,388,608
    unsigned short* qb    = (unsigned short*)(ws + 8388608);    //  8,388,608
    unsigned short* kb    = (unsigned short*)(ws + 16777216);   //  8,388,608
    unsigned short* vTb   = (unsigned short*)(ws + 25165824);   //  8,388,608
    unsigned short* ckvb0 = (unsigned short*)(ws + 33554432);   //  4,194,304
    unsigned short* aob   = (unsigned short*)(ws + 37748736);   //  8,388,608
    unsigned short* wcomb = (unsigned short*)(ws + 46137344);   //    786,432
    unsigned short* wkub  = (unsigned short*)(ws + 46923776);   //    524,288
    unsigned short* woutb = (unsigned short*)(ws + 47448064);   //    524,288
    float*          cosT  = (float*)(ws + 48005120);            //    262,144
    float*          sinT  = (float*)(ws + 48267264);            //    262,144
    float*          ssum  = (float*)(ws + 48529408);            //    131,072 [4][8192]

    prep_kernel<<<5248, 256, 0, stream>>>(x, Wq, Wkd, Wku, wnorm, Wout,
                                          xb, wcomb, wkub, woutb, cosT, sinT);

    // fused q + kv_down projection (+ q-RoPE, ckv write, sumsq partials): [8192, 768]
    gemm_bf<1, 128><<<dim3(BT / 128, 6), 512, 0, stream>>>(xb, wcomb, nullptr, qb, ckvb0,
                                                           cosT, sinT, ssum, DIMM, 768);

    // kv up-projection (+ k-RoPE*rinv, V^T pack*rinv; rinv from ssum): [8192, 1024]
    gemm_bf<2, 128><<<dim3(BT / 128, 8), 512, 0, stream>>>(ckvb0, wkub, nullptr, kb, vTb,
                                                           cosT, sinT, ssum, RANKK, 1024);

    // attention: 512 blocks, 512 thr (8 waves x 16 queries)
    attn_mfma<<<512, 512, 0, stream>>>(qb, kb, vTb, aob);

    // out = aob @ Wout^T (f32), BM=64 (512 blocks)
    gemm_bf<0, 64><<<dim3(BT / 64, 4), 256, 0, stream>>>(aob, woutb, out, nullptr, nullptr,
                                                         nullptr, nullptr, nullptr, DIMM, DIMM);
}